// Round 4
// baseline (625.780 us; speedup 1.0000x reference)
//
#include <hip/hip_runtime.h>
#include <hip/hip_fp16.h>

#define NG    64           // N_GRIDS
#define NC    2            // FEATS
#define DIMG  64           // DIM
#define NPTS  (1u << 19)   // N_PTS
#define NN    64           // N_NEURONS
#define DIN   (NG * NC)    // 128
#define VOX   (DIMG * DIMG * DIMG)
#define CELLS 16
#define NCELL (CELLS * CELLS * CELLS)

typedef _Float16 f16;
typedef _Float16 f16x8 __attribute__((ext_vector_type(8)));
typedef float    f32x4 __attribute__((ext_vector_type(4)));

// ws layout (float offsets) — split path
#define OFF_M      0           // 768
#define OFF_W0F    768         // 4096 (8192 f16)
#define OFF_W1F    4864        // 2048 (4096 f16)
#define OFF_HIST   6912        // 4096 uint
#define OFF_CNT    11008       // 4096 uint
#define OFF_SORT   15104       // NPTS*4
#define OFF_AFRAG  2112256     // NPTS*64 floats (NPTS*128 f16)
#define OFF_FEATR_SPLIT 35666688  // NG*VOX uint
#define WS_SPLIT_BYTES ((size_t)(OFF_FEATR_SPLIT + (size_t)NG * VOX) * 4)
// mid (fused) path puts featR right after sorted:
#define OFF_FEATR_MID  2112256
#define WS_MID_BYTES ((size_t)(OFF_FEATR_MID + (size_t)NG * VOX) * 4)

__device__ __forceinline__ f16x8 as_f16x8(uint4 u) {
    union { uint4 u; f16x8 h; } c; c.u = u; return c.h;
}

__global__ void prep_kernel(const float* __restrict__ r, const float* __restrict__ s,
                            const float* __restrict__ t, const float* __restrict__ W0,
                            const float* __restrict__ W1, float* __restrict__ ws) {
    int tid = blockIdx.x * blockDim.x + threadIdx.x;
    int nth = gridDim.x * blockDim.x;
    float* M  = ws + OFF_M;
    f16* W0f  = (f16*)(ws + OFF_W0F);
    f16* W1f  = (f16*)(ws + OFF_W1F);
    if (tid < NG) {
        float qw = r[tid*4+0], qx = r[tid*4+1], qy = r[tid*4+2], qz = r[tid*4+3];
        float inv = 1.0f / sqrtf(qw*qw + qx*qx + qy*qy + qz*qz);
        qw *= inv; qx *= inv; qy *= inv; qz *= inv;
        float R0 = 1.f - 2.f*(qy*qy + qz*qz), R1 = 2.f*(qx*qy - qw*qz), R2 = 2.f*(qx*qz + qw*qy);
        float R3 = 2.f*(qx*qy + qw*qz), R4 = 1.f - 2.f*(qx*qx + qz*qz), R5 = 2.f*(qy*qz - qw*qx);
        float R6 = 2.f*(qx*qz - qw*qy), R7 = 2.f*(qy*qz + qw*qx), R8 = 1.f - 2.f*(qx*qx + qy*qy);
        float s0 = s[tid*3+0], s1 = s[tid*3+1], s2 = s[tid*3+2];
        M[tid*12+ 0] = s0*R0; M[tid*12+ 1] = s0*R1; M[tid*12+ 2] = s0*R2; M[tid*12+ 3] = t[tid*3+0];
        M[tid*12+ 4] = s1*R3; M[tid*12+ 5] = s1*R4; M[tid*12+ 6] = s1*R5; M[tid*12+ 7] = t[tid*3+1];
        M[tid*12+ 8] = s2*R6; M[tid*12+ 9] = s2*R7; M[tid*12+10] = s2*R8; M[tid*12+11] = t[tid*3+2];
    }
    for (int idx = tid; idx < 4*4*64*8; idx += nth) {
        int tn = idx >> 11, kc = (idx >> 9) & 3, lane = (idx >> 3) & 63, j = idx & 7;
        int n = tn*16 + (lane & 15);
        int k = kc*32 + (lane >> 4)*8 + j;
        W0f[idx] = (f16)W0[n*DIN + k];
    }
    for (int idx = tid; idx < 4*2*64*8; idx += nth) {
        int tn = idx >> 10, kc2 = (idx >> 9) & 1, lane = (idx >> 3) & 63, j = idx & 7;
        int n = tn*16 + (lane & 15);
        int k = kc2*32 + (lane >> 4)*8 + j;
        W1f[idx] = (f16)W1[n*NN + k];
    }
}

__global__ __launch_bounds__(256) void repack_kernel(const float* __restrict__ feat,
                                                     uint4* __restrict__ featR) {
    size_t i = (size_t)blockIdx.x * 256 + threadIdx.x;   // over NG*VOX/4
    size_t g = i / (VOX/4), vq = i % (VOX/4);
    const float4* p0 = (const float4*)(feat + g * (size_t)(NC * VOX));
    const float4* p1 = (const float4*)(feat + g * (size_t)(NC * VOX) + VOX);
    float4 a = p0[vq], b = p1[vq];
    union { uint4 u; __half2 h[4]; } o;
    o.h[0] = __floats2half2_rn(a.x, b.x);
    o.h[1] = __floats2half2_rn(a.y, b.y);
    o.h[2] = __floats2half2_rn(a.z, b.z);
    o.h[3] = __floats2half2_rn(a.w, b.w);
    featR[i] = o.u;
}

__device__ __forceinline__ int cell_of(float px, float py, float pz) {
    int ix = (int)((px + 1.f) * (0.5f * CELLS)); ix = ix < 0 ? 0 : (ix > CELLS-1 ? CELLS-1 : ix);
    int iy = (int)((py + 1.f) * (0.5f * CELLS)); iy = iy < 0 ? 0 : (iy > CELLS-1 ? CELLS-1 : iy);
    int iz = (int)((pz + 1.f) * (0.5f * CELLS)); iz = iz < 0 ? 0 : (iz > CELLS-1 ? CELLS-1 : iz);
    return (iz * CELLS + iy) * CELLS + ix;
}

__global__ __launch_bounds__(256) void count_kernel(const float* __restrict__ xs,
                                                    unsigned* __restrict__ hist) {
    unsigned pt = blockIdx.x * blockDim.x + threadIdx.x;
    atomicAdd(&hist[cell_of(xs[pt*3+0], xs[pt*3+1], xs[pt*3+2])], 1u);
}

__global__ __launch_bounds__(256) void scan_kernel(const unsigned* __restrict__ hist,
                                                   unsigned* __restrict__ cnt) {
    __shared__ unsigned part[256];
    int t = threadIdx.x;
    unsigned base = t * (NCELL / 256);
    unsigned loc[NCELL / 256];
    unsigned sum = 0;
#pragma unroll
    for (int i = 0; i < NCELL / 256; ++i) { loc[i] = sum; sum += hist[base + i]; }
    part[t] = sum;
    __syncthreads();
    for (int off = 1; off < 256; off <<= 1) {
        unsigned v = (t >= off) ? part[t - off] : 0u;
        __syncthreads();
        part[t] += v;
        __syncthreads();
    }
    unsigned prev = (t == 0) ? 0u : part[t - 1];
#pragma unroll
    for (int i = 0; i < NCELL / 256; ++i) cnt[base + i] = prev + loc[i];
}

__global__ __launch_bounds__(256) void scatter_kernel(const float* __restrict__ xs,
                                                      unsigned* __restrict__ cnt,
                                                      float4* __restrict__ sorted) {
    unsigned pt = blockIdx.x * blockDim.x + threadIdx.x;
    float px = xs[pt*3+0], py = xs[pt*3+1], pz = xs[pt*3+2];
    unsigned pos = atomicAdd(&cnt[cell_of(px, py, pz)], 1u);
    sorted[pos] = make_float4(px, py, pz, __int_as_float((int)pt));
}

// Sample one point's 128 f16 features; store A-fragment-linear:
// Afrag[(mtile*4+kc)*64 + koct*16 + mrow] = uint4 of 4 half2 (grids kc*16+koct*4+{0..3})
__global__ __launch_bounds__(256, 8) void sample_kernel(
        const float4* __restrict__ sorted, const __half2* __restrict__ featR,
        const float* __restrict__ ws, uint4* __restrict__ Afrag) {
    const float* M = ws + OFF_M;
    unsigned i = blockIdx.x * 256u + threadIdx.x;
    float4 p4 = sorted[i];
    float px = p4.x, py = p4.y, pz = p4.z;
    unsigned mtile = i >> 4, mrow = i & 15;

    for (int kc = 0; kc < 4; ++kc) {
        for (int c = 0; c < 4; ++c) {
            uint pk[4];
#pragma unroll
            for (int gi = 0; gi < 4; ++gi) {
                int g = kc * 16 + c * 4 + gi;
                const float* m = M + g * 12;          // uniform -> s_load
                float tx = m[0]*px + m[1]*py + m[2]*pz + m[3];
                float ty = m[4]*px + m[5]*py + m[6]*pz + m[7];
                float tz = m[8]*px + m[9]*py + m[10]*pz + m[11];
                float gx = (tx + 1.f) * (0.5f * (DIMG - 1));
                float gy = (ty + 1.f) * (0.5f * (DIMG - 1));
                float gz = (tz + 1.f) * (0.5f * (DIMG - 1));
                float f0 = 0.f, f1 = 0.f;
                if (gx > -1.f && gx < (float)DIMG && gy > -1.f && gy < (float)DIMG &&
                    gz > -1.f && gz < (float)DIMG) {
                    float x0f = floorf(gx), y0f = floorf(gy), z0f = floorf(gz);
                    float fx = gx - x0f, fy = gy - y0f, fz = gz - z0f;
                    int x0 = (int)x0f, y0 = (int)y0f, z0 = (int)z0f;
                    int x1 = x0 + 1, y1 = y0 + 1, z1 = z0 + 1;
                    float wx0 = (x0 >= 0)      ? (1.f - fx) : 0.f;
                    float wx1 = (x1 <= DIMG-1) ? fx         : 0.f;
                    float wy0 = (y0 >= 0)      ? (1.f - fy) : 0.f;
                    float wy1 = (y1 <= DIMG-1) ? fy         : 0.f;
                    float wz0 = (z0 >= 0)      ? (1.f - fz) : 0.f;
                    float wz1 = (z1 <= DIMG-1) ? fz         : 0.f;
                    int cx0 = max(x0, 0), cx1 = min(x1, DIMG-1);
                    int cy0 = max(y0, 0), cy1 = min(y1, DIMG-1);
                    int cz0 = max(z0, 0), cz1 = min(z1, DIMG-1);
                    const __half2* b = featR + (size_t)g * VOX;
                    int r00 = (cz0 * DIMG + cy0) * DIMG;
                    int r01 = (cz0 * DIMG + cy1) * DIMG;
                    int r10 = (cz1 * DIMG + cy0) * DIMG;
                    int r11 = (cz1 * DIMG + cy1) * DIMG;
                    float2 v000 = __half22float2(b[r00+cx0]), v100 = __half22float2(b[r00+cx1]);
                    float2 v010 = __half22float2(b[r01+cx0]), v110 = __half22float2(b[r01+cx1]);
                    float2 v001 = __half22float2(b[r10+cx0]), v101 = __half22float2(b[r10+cx1]);
                    float2 v011 = __half22float2(b[r11+cx0]), v111 = __half22float2(b[r11+cx1]);
                    float w00 = wz0*wy0, w01 = wz0*wy1, w10 = wz1*wy0, w11 = wz1*wy1;
                    f0 = w00*(wx0*v000.x + wx1*v100.x) + w01*(wx0*v010.x + wx1*v110.x)
                       + w10*(wx0*v001.x + wx1*v101.x) + w11*(wx0*v011.x + wx1*v111.x);
                    f1 = w00*(wx0*v000.y + wx1*v100.y) + w01*(wx0*v010.y + wx1*v110.y)
                       + w10*(wx0*v001.y + wx1*v101.y) + w11*(wx0*v011.y + wx1*v111.y);
                }
                union { uint u; __half2 h; } pkc;
                pkc.h = __floats2half2_rn(f0, f1);
                pk[gi] = pkc.u;
            }
            Afrag[(mtile * 4 + kc) * 64 + c * 16 + mrow] = make_uint4(pk[0], pk[1], pk[2], pk[3]);
        }
    }
}

// MLP over A-fragments: layer0 MFMA (A from global), relu -> LDS, layer1 MFMA, dot W2
__global__ __launch_bounds__(256) void mlp_kernel(
        const float4* __restrict__ sorted, const uint4* __restrict__ Afrag,
        const float* __restrict__ ws, const float* __restrict__ W2,
        float* __restrict__ out) {
    __shared__ uint4 SH[2048];     // 32 KB H0 frag-linear
    __shared__ float SOUT[256];
    const f16x8* W0f = (const f16x8*)(ws + OFF_W0F);
    const f16x8* W1f = (const f16x8*)(ws + OFF_W1F);

    int t = threadIdx.x;
    int lane = t & 63, w = t >> 6;

    int orig = __float_as_int(sorted[blockIdx.x * 256u + t].w);

    f32x4 acc[4][4];
#pragma unroll
    for (int a = 0; a < 4; ++a)
#pragma unroll
        for (int b = 0; b < 4; ++b) acc[a][b] = (f32x4){0.f, 0.f, 0.f, 0.f};

#pragma unroll
    for (int kc = 0; kc < 4; ++kc) {
#pragma unroll
        for (int im = 0; im < 4; ++im) {
            unsigned mtile = blockIdx.x * 16u + w * 4 + im;
            f16x8 af = as_f16x8(Afrag[(mtile * 4 + kc) * 64u + lane]);
#pragma unroll
            for (int tn = 0; tn < 4; ++tn) {
                f16x8 bf = W0f[(tn * 4 + kc) * 64 + lane];
                acc[im][tn] = __builtin_amdgcn_mfma_f32_16x16x32_f16(af, bf, acc[im][tn], 0, 0, 0);
            }
        }
    }

    // relu(h0) -> H0 frag-linear f16 in SH
    f16* Hh = (f16*)SH;
#pragma unroll
    for (int im = 0; im < 4; ++im) {
        int tm = w * 4 + im;
#pragma unroll
        for (int tn = 0; tn < 4; ++tn) {
            int n = tn * 16 + (lane & 15);
            int kc2 = n >> 5, koct = (n >> 3) & 3, j = n & 7;
#pragma unroll
            for (int r = 0; r < 4; ++r) {
                int mloc = (lane >> 4) * 4 + r;
                Hh[tm * 1024 + kc2 * 512 + (koct * 16 + mloc) * 8 + j] =
                    (f16)fmaxf(acc[im][tn][r], 0.f);
            }
        }
    }
    __syncthreads();

    f32x4 acc2[4][4];
#pragma unroll
    for (int a = 0; a < 4; ++a)
#pragma unroll
        for (int b = 0; b < 4; ++b) acc2[a][b] = (f32x4){0.f, 0.f, 0.f, 0.f};
#pragma unroll
    for (int kc2 = 0; kc2 < 2; ++kc2) {
#pragma unroll
        for (int im = 0; im < 4; ++im) {
            f16x8 af = as_f16x8(SH[(w * 4 + im) * 128 + kc2 * 64 + lane]);
#pragma unroll
            for (int tn = 0; tn < 4; ++tn) {
                f16x8 bf = W1f[(tn * 2 + kc2) * 64 + lane];
                acc2[im][tn] = __builtin_amdgcn_mfma_f32_16x16x32_f16(af, bf, acc2[im][tn], 0, 0, 0);
            }
        }
    }

    float w2v[4];
#pragma unroll
    for (int tn = 0; tn < 4; ++tn) w2v[tn] = W2[tn * 16 + (lane & 15)];
    __syncthreads();
#pragma unroll
    for (int im = 0; im < 4; ++im) {
#pragma unroll
        for (int r = 0; r < 4; ++r) {
            float pp = 0.f;
#pragma unroll
            for (int tn = 0; tn < 4; ++tn) pp += fmaxf(acc2[im][tn][r], 0.f) * w2v[tn];
            pp += __shfl_xor(pp, 1);
            pp += __shfl_xor(pp, 2);
            pp += __shfl_xor(pp, 4);
            pp += __shfl_xor(pp, 8);
            if ((lane & 15) == 0)
                SOUT[w * 64 + im * 16 + (lane >> 4) * 4 + r] = pp;
        }
    }
    __syncthreads();
    out[orig] = SOUT[t];
}

// ---------------- mid fallback: round-3 fused kernel ----------------
__global__ __launch_bounds__(256, 4) void amgsrn_fused(
        const float4* __restrict__ sorted, const __half2* __restrict__ featR,
        const float* __restrict__ ws, const float* __restrict__ W2,
        float* __restrict__ out) {
    __shared__ uint4 SH[2048];
    __shared__ float SOUT[256];
    const float* M = ws + OFF_M;
    const f16x8* W0f = (const f16x8*)(ws + OFF_W0F);
    const f16x8* W1f = (const f16x8*)(ws + OFF_W1F);

    int t = threadIdx.x;
    int lane = t & 63, w = t >> 6;
    int tmw = t >> 4, mrow = t & 15;

    float4 p4 = sorted[blockIdx.x * 256u + t];
    float px = p4.x, py = p4.y, pz = p4.z;
    int orig = __float_as_int(p4.w);

    f32x4 acc[4][4];
#pragma unroll
    for (int a = 0; a < 4; ++a)
#pragma unroll
        for (int b = 0; b < 4; ++b) acc[a][b] = (f32x4){0.f, 0.f, 0.f, 0.f};

    for (int kc = 0; kc < 4; ++kc) {
        uint4* buf = &SH[(kc & 1) * 1024];
#pragma unroll
        for (int c = 0; c < 4; ++c) {
            uint pk[4];
#pragma unroll
            for (int gi = 0; gi < 4; ++gi) {
                int g = kc * 16 + c * 4 + gi;
                const float* m = M + g * 12;
                float tx = m[0]*px + m[1]*py + m[2]*pz + m[3];
                float ty = m[4]*px + m[5]*py + m[6]*pz + m[7];
                float tz = m[8]*px + m[9]*py + m[10]*pz + m[11];
                float gx = (tx + 1.f) * (0.5f * (DIMG - 1));
                float gy = (ty + 1.f) * (0.5f * (DIMG - 1));
                float gz = (tz + 1.f) * (0.5f * (DIMG - 1));
                float f0 = 0.f, f1 = 0.f;
                if (gx > -1.f && gx < (float)DIMG && gy > -1.f && gy < (float)DIMG &&
                    gz > -1.f && gz < (float)DIMG) {
                    float x0f = floorf(gx), y0f = floorf(gy), z0f = floorf(gz);
                    float fx = gx - x0f, fy = gy - y0f, fz = gz - z0f;
                    int x0 = (int)x0f, y0 = (int)y0f, z0 = (int)z0f;
                    int x1 = x0 + 1, y1 = y0 + 1, z1 = z0 + 1;
                    float wx0 = (x0 >= 0)      ? (1.f - fx) : 0.f;
                    float wx1 = (x1 <= DIMG-1) ? fx         : 0.f;
                    float wy0 = (y0 >= 0)      ? (1.f - fy) : 0.f;
                    float wy1 = (y1 <= DIMG-1) ? fy         : 0.f;
                    float wz0 = (z0 >= 0)      ? (1.f - fz) : 0.f;
                    float wz1 = (z1 <= DIMG-1) ? fz         : 0.f;
                    int cx0 = max(x0, 0), cx1 = min(x1, DIMG-1);
                    int cy0 = max(y0, 0), cy1 = min(y1, DIMG-1);
                    int cz0 = max(z0, 0), cz1 = min(z1, DIMG-1);
                    const __half2* b = featR + (size_t)g * VOX;
                    int r00 = (cz0 * DIMG + cy0) * DIMG;
                    int r01 = (cz0 * DIMG + cy1) * DIMG;
                    int r10 = (cz1 * DIMG + cy0) * DIMG;
                    int r11 = (cz1 * DIMG + cy1) * DIMG;
                    float2 v000 = __half22float2(b[r00+cx0]), v100 = __half22float2(b[r00+cx1]);
                    float2 v010 = __half22float2(b[r01+cx0]), v110 = __half22float2(b[r01+cx1]);
                    float2 v001 = __half22float2(b[r10+cx0]), v101 = __half22float2(b[r10+cx1]);
                    float2 v011 = __half22float2(b[r11+cx0]), v111 = __half22float2(b[r11+cx1]);
                    float w00 = wz0*wy0, w01 = wz0*wy1, w10 = wz1*wy0, w11 = wz1*wy1;
                    f0 = w00*(wx0*v000.x + wx1*v100.x) + w01*(wx0*v010.x + wx1*v110.x)
                       + w10*(wx0*v001.x + wx1*v101.x) + w11*(wx0*v011.x + wx1*v111.x);
                    f1 = w00*(wx0*v000.y + wx1*v100.y) + w01*(wx0*v010.y + wx1*v110.y)
                       + w10*(wx0*v001.y + wx1*v101.y) + w11*(wx0*v011.y + wx1*v111.y);
                }
                union { uint u; __half2 h; } pkc;
                pkc.h = __floats2half2_rn(f0, f1);
                pk[gi] = pkc.u;
            }
            buf[tmw * 64 + c * 16 + mrow] = make_uint4(pk[0], pk[1], pk[2], pk[3]);
        }
        __syncthreads();
#pragma unroll
        for (int im = 0; im < 4; ++im) {
            f16x8 af = as_f16x8(buf[(w * 4 + im) * 64 + lane]);
#pragma unroll
            for (int tn = 0; tn < 4; ++tn) {
                f16x8 bf = W0f[(tn * 4 + kc) * 64 + lane];
                acc[im][tn] = __builtin_amdgcn_mfma_f32_16x16x32_f16(af, bf, acc[im][tn], 0, 0, 0);
            }
        }
    }
    __syncthreads();

    f16* Hh = (f16*)SH;
#pragma unroll
    for (int im = 0; im < 4; ++im) {
        int tm = w * 4 + im;
#pragma unroll
        for (int tn = 0; tn < 4; ++tn) {
            int n = tn * 16 + (lane & 15);
            int kc2 = n >> 5, koct = (n >> 3) & 3, j = n & 7;
#pragma unroll
            for (int r = 0; r < 4; ++r) {
                int mloc = (lane >> 4) * 4 + r;
                Hh[tm * 1024 + kc2 * 512 + (koct * 16 + mloc) * 8 + j] =
                    (f16)fmaxf(acc[im][tn][r], 0.f);
            }
        }
    }
    __syncthreads();

    f32x4 acc2[4][4];
#pragma unroll
    for (int a = 0; a < 4; ++a)
#pragma unroll
        for (int b = 0; b < 4; ++b) acc2[a][b] = (f32x4){0.f, 0.f, 0.f, 0.f};
#pragma unroll
    for (int kc2 = 0; kc2 < 2; ++kc2) {
#pragma unroll
        for (int im = 0; im < 4; ++im) {
            f16x8 af = as_f16x8(SH[(w * 4 + im) * 128 + kc2 * 64 + lane]);
#pragma unroll
            for (int tn = 0; tn < 4; ++tn) {
                f16x8 bf = W1f[(tn * 2 + kc2) * 64 + lane];
                acc2[im][tn] = __builtin_amdgcn_mfma_f32_16x16x32_f16(af, bf, acc2[im][tn], 0, 0, 0);
            }
        }
    }

    float w2v[4];
#pragma unroll
    for (int tn = 0; tn < 4; ++tn) w2v[tn] = W2[tn * 16 + (lane & 15)];
    __syncthreads();
#pragma unroll
    for (int im = 0; im < 4; ++im) {
#pragma unroll
        for (int r = 0; r < 4; ++r) {
            float pp = 0.f;
#pragma unroll
            for (int tn = 0; tn < 4; ++tn) pp += fmaxf(acc2[im][tn][r], 0.f) * w2v[tn];
            pp += __shfl_xor(pp, 1);
            pp += __shfl_xor(pp, 2);
            pp += __shfl_xor(pp, 4);
            pp += __shfl_xor(pp, 8);
            if ((lane & 15) == 0)
                SOUT[w * 64 + im * 16 + (lane >> 4) * 4 + r] = pp;
        }
    }
    __syncthreads();
    out[orig] = SOUT[t];
}

// ---------------- final fallback (fp32, unsorted) ----------------
__global__ __launch_bounds__(256) void amgsrn_fallback(
        const float* __restrict__ xs, const float* __restrict__ feat,
        const float* __restrict__ ws, const float* __restrict__ W0,
        const float* __restrict__ W1, const float* __restrict__ W2,
        float* __restrict__ out) {
    const float* M = ws + OFF_M;
    unsigned pt = blockIdx.x * blockDim.x + threadIdx.x;
    float px = xs[pt*3+0], py = xs[pt*3+1], pz = xs[pt*3+2];
    float h0[NN];
#pragma unroll
    for (int j = 0; j < NN; ++j) h0[j] = 0.f;
    for (int g = 0; g < NG; ++g) {
        const float* m = M + g * 12;
        float tx = m[0]*px + m[1]*py + m[2]*pz + m[3];
        float ty = m[4]*px + m[5]*py + m[6]*pz + m[7];
        float tz = m[8]*px + m[9]*py + m[10]*pz + m[11];
        float gx = (tx + 1.f) * (0.5f * (DIMG - 1));
        float gy = (ty + 1.f) * (0.5f * (DIMG - 1));
        float gz = (tz + 1.f) * (0.5f * (DIMG - 1));
        float f0 = 0.f, f1 = 0.f;
        if (gx > -1.f && gx < (float)DIMG && gy > -1.f && gy < (float)DIMG &&
            gz > -1.f && gz < (float)DIMG) {
            float x0f = floorf(gx), y0f = floorf(gy), z0f = floorf(gz);
            float fx = gx - x0f, fy = gy - y0f, fz = gz - z0f;
            int x0 = (int)x0f, y0 = (int)y0f, z0 = (int)z0f;
            int x1 = x0 + 1, y1 = y0 + 1, z1 = z0 + 1;
            float wx0 = (x0 >= 0)      ? (1.f - fx) : 0.f;
            float wx1 = (x1 <= DIMG-1) ? fx         : 0.f;
            float wy0 = (y0 >= 0)      ? (1.f - fy) : 0.f;
            float wy1 = (y1 <= DIMG-1) ? fy         : 0.f;
            float wz0 = (z0 >= 0)      ? (1.f - fz) : 0.f;
            float wz1 = (z1 <= DIMG-1) ? fz         : 0.f;
            int cx0 = max(x0, 0), cx1 = min(x1, DIMG-1);
            int cy0 = max(y0, 0), cy1 = min(y1, DIMG-1);
            int cz0 = max(z0, 0), cz1 = min(z1, DIMG-1);
            const float* b0 = feat + (size_t)g * (NC * VOX);
            const float* b1 = b0 + VOX;
            int r00 = (cz0 * DIMG + cy0) * DIMG;
            int r01 = (cz0 * DIMG + cy1) * DIMG;
            int r10 = (cz1 * DIMG + cy0) * DIMG;
            int r11 = (cz1 * DIMG + cy1) * DIMG;
            f0 = wz0*(wy0*(wx0*b0[r00+cx0] + wx1*b0[r00+cx1]) + wy1*(wx0*b0[r01+cx0] + wx1*b0[r01+cx1]))
               + wz1*(wy0*(wx0*b0[r10+cx0] + wx1*b0[r10+cx1]) + wy1*(wx0*b0[r11+cx0] + wx1*b0[r11+cx1]));
            f1 = wz0*(wy0*(wx0*b1[r00+cx0] + wx1*b1[r00+cx1]) + wy1*(wx0*b1[r01+cx0] + wx1*b1[r01+cx1]))
               + wz1*(wy0*(wx0*b1[r10+cx0] + wx1*b1[r10+cx1]) + wy1*(wx0*b1[r11+cx0] + wx1*b1[r11+cx1]));
        }
#pragma unroll
        for (int j = 0; j < NN; ++j) {
            h0[j] = fmaf(f0, W0[j*DIN + g*2 + 0], h0[j]);
            h0[j] = fmaf(f1, W0[j*DIN + g*2 + 1], h0[j]);
        }
    }
#pragma unroll
    for (int j = 0; j < NN; ++j) h0[j] = fmaxf(h0[j], 0.f);
    float outv = 0.f;
    for (int j = 0; j < NN; ++j) {
        float acc = 0.f;
#pragma unroll
        for (int k = 0; k < NN; ++k) acc = fmaf(h0[k], W1[j*NN + k], acc);
        outv = fmaf(fmaxf(acc, 0.f), W2[j], outv);
    }
    out[pt] = outv;
}

extern "C" void kernel_launch(void* const* d_in, const int* in_sizes, int n_in,
                              void* d_out, int out_size, void* d_ws, size_t ws_size,
                              hipStream_t stream) {
    const float* x    = (const float*)d_in[0];
    const float* r    = (const float*)d_in[1];
    const float* s    = (const float*)d_in[2];
    const float* t    = (const float*)d_in[3];
    const float* feat = (const float*)d_in[4];
    const float* W0   = (const float*)d_in[5];
    const float* W1   = (const float*)d_in[6];
    const float* W2   = (const float*)d_in[7];
    float* outp = (float*)d_out;
    float* ws   = (float*)d_ws;

    prep_kernel<<<64, 256, 0, stream>>>(r, s, t, W0, W1, ws);

    unsigned* hist   = (unsigned*)(ws + OFF_HIST);
    unsigned* cnt    = (unsigned*)(ws + OFF_CNT);
    float4*   sorted = (float4*)(ws + OFF_SORT);

    if (ws_size >= WS_SPLIT_BYTES) {
        uint4* Afrag = (uint4*)(ws + OFF_AFRAG);
        uint4* featR = (uint4*)(ws + OFF_FEATR_SPLIT);
        hipMemsetAsync(hist, 0, NCELL * sizeof(unsigned), stream);
        repack_kernel<<<(NG * VOX / 4) / 256, 256, 0, stream>>>(feat, featR);
        count_kernel<<<NPTS / 256, 256, 0, stream>>>(x, hist);
        scan_kernel<<<1, 256, 0, stream>>>(hist, cnt);
        scatter_kernel<<<NPTS / 256, 256, 0, stream>>>(x, cnt, sorted);
        sample_kernel<<<NPTS / 256, 256, 0, stream>>>(sorted, (const __half2*)featR, ws, Afrag);
        mlp_kernel<<<NPTS / 256, 256, 0, stream>>>(sorted, Afrag, ws, W2, outp);
    } else if (ws_size >= WS_MID_BYTES) {
        uint4* featR = (uint4*)(ws + OFF_FEATR_MID);
        hipMemsetAsync(hist, 0, NCELL * sizeof(unsigned), stream);
        repack_kernel<<<(NG * VOX / 4) / 256, 256, 0, stream>>>(feat, featR);
        count_kernel<<<NPTS / 256, 256, 0, stream>>>(x, hist);
        scan_kernel<<<1, 256, 0, stream>>>(hist, cnt);
        scatter_kernel<<<NPTS / 256, 256, 0, stream>>>(x, cnt, sorted);
        amgsrn_fused<<<NPTS / 256, 256, 0, stream>>>(sorted, (const __half2*)featR, ws, W2, outp);
    } else {
        amgsrn_fallback<<<NPTS / 256, 256, 0, stream>>>(x, feat, ws, W0, W1, W2, outp);
    }
}

// Round 5
// 466.609 us; speedup vs baseline: 1.3411x; 1.3411x over previous
//
#include <hip/hip_runtime.h>
#include <hip/hip_fp16.h>

#define NG    64           // N_GRIDS
#define NC    2            // FEATS
#define DIMG  64           // DIM
#define NPTS  (1u << 19)   // N_PTS
#define NN    64           // N_NEURONS
#define DIN   (NG * NC)    // 128
#define VOX   (DIMG * DIMG * DIMG)
#define CELLS 16
#define NCELL (CELLS * CELLS * CELLS)

typedef _Float16 f16;
typedef _Float16 f16x8 __attribute__((ext_vector_type(8)));
typedef float    f32x4 __attribute__((ext_vector_type(4)));

// ws layout (float offsets)
#define OFF_M      0           // 768
#define OFF_W0F    768         // 4096 floats (8192 f16)
#define OFF_W1F    4864        // 2048 floats (4096 f16)
#define OFF_HIST   6912        // 4096 uint
#define OFF_CNT    11008       // 4096 uint
#define OFF_SORT   15104       // NPTS*4 floats
#define OFF_FEATP  2112256     // NG*VOX uint2 (duplicated x-pairs) = 2*NG*VOX floats
#define WS_REQ_BYTES (((size_t)OFF_FEATP + 2ull * NG * VOX) * 4 + 64)

__device__ __forceinline__ f16x8 as_f16x8(uint4 u) {
    union { uint4 u; f16x8 h; } c; c.u = u; return c.h;
}
__device__ __forceinline__ float2 h2f(uint u) {
    union { uint u; __half2 h; } c; c.u = u; return __half22float2(c.h);
}

__global__ void prep_kernel(const float* __restrict__ r, const float* __restrict__ s,
                            const float* __restrict__ t, const float* __restrict__ W0,
                            const float* __restrict__ W1, float* __restrict__ ws) {
    int tid = blockIdx.x * blockDim.x + threadIdx.x;
    int nth = gridDim.x * blockDim.x;
    float* M  = ws + OFF_M;
    f16* W0f  = (f16*)(ws + OFF_W0F);
    f16* W1f  = (f16*)(ws + OFF_W1F);
    if (tid < NG) {
        float qw = r[tid*4+0], qx = r[tid*4+1], qy = r[tid*4+2], qz = r[tid*4+3];
        float inv = 1.0f / sqrtf(qw*qw + qx*qx + qy*qy + qz*qz);
        qw *= inv; qx *= inv; qy *= inv; qz *= inv;
        float R0 = 1.f - 2.f*(qy*qy + qz*qz), R1 = 2.f*(qx*qy - qw*qz), R2 = 2.f*(qx*qz + qw*qy);
        float R3 = 2.f*(qx*qy + qw*qz), R4 = 1.f - 2.f*(qx*qx + qz*qz), R5 = 2.f*(qy*qz - qw*qx);
        float R6 = 2.f*(qx*qz - qw*qy), R7 = 2.f*(qy*qz + qw*qx), R8 = 1.f - 2.f*(qx*qx + qy*qy);
        float s0 = s[tid*3+0], s1 = s[tid*3+1], s2 = s[tid*3+2];
        M[tid*12+ 0] = s0*R0; M[tid*12+ 1] = s0*R1; M[tid*12+ 2] = s0*R2; M[tid*12+ 3] = t[tid*3+0];
        M[tid*12+ 4] = s1*R3; M[tid*12+ 5] = s1*R4; M[tid*12+ 6] = s1*R5; M[tid*12+ 7] = t[tid*3+1];
        M[tid*12+ 8] = s2*R6; M[tid*12+ 9] = s2*R7; M[tid*12+10] = s2*R8; M[tid*12+11] = t[tid*3+2];
    }
    for (int idx = tid; idx < 4*4*64*8; idx += nth) {
        int tn = idx >> 11, kc = (idx >> 9) & 3, lane = (idx >> 3) & 63, j = idx & 7;
        int n = tn*16 + (lane & 15);
        int k = kc*32 + (lane >> 4)*8 + j;
        W0f[idx] = (f16)W0[n*DIN + k];
    }
    for (int idx = tid; idx < 4*2*64*8; idx += nth) {
        int tn = idx >> 10, kc2 = (idx >> 9) & 1, lane = (idx >> 3) & 63, j = idx & 7;
        int n = tn*16 + (lane & 15);
        int k = kc2*32 + (lane >> 4)*8 + j;
        W1f[idx] = (f16)W1[n*NN + k];
    }
}

// fp32 [g][c][v] -> duplicated-pair f16: featP[g*VOX+v] = (half2(v), half2(v+1)), 8B aligned
__global__ __launch_bounds__(256) void repack_pairs(const float* __restrict__ feat,
                                                    uint4* __restrict__ featP4) {
    size_t i = (size_t)blockIdx.x * 256 + threadIdx.x;   // over NG*VOX/4
    size_t g = i / (VOX/4), vq = i % (VOX/4);
    const float* b0 = feat + g * (size_t)(NC * VOX);
    const float* b1 = b0 + VOX;
    float4 a = ((const float4*)b0)[vq];
    float4 b = ((const float4*)b1)[vq];
    int vnext = (int)vq * 4 + 4; if (vnext > VOX - 1) vnext = VOX - 1;
    float a4 = b0[vnext], b4 = b1[vnext];
    __half2 h0 = __floats2half2_rn(a.x, b.x);
    __half2 h1 = __floats2half2_rn(a.y, b.y);
    __half2 h2 = __floats2half2_rn(a.z, b.z);
    __half2 h3 = __floats2half2_rn(a.w, b.w);
    __half2 h4 = __floats2half2_rn(a4, b4);
    union { uint4 u[2]; __half2 h[8]; } o;
    o.h[0] = h0; o.h[1] = h1;
    o.h[2] = h1; o.h[3] = h2;
    o.h[4] = h2; o.h[5] = h3;
    o.h[6] = h3; o.h[7] = h4;
    featP4[i*2 + 0] = o.u[0];
    featP4[i*2 + 1] = o.u[1];
}

__device__ __forceinline__ int cell_of(float px, float py, float pz) {
    int ix = (int)((px + 1.f) * (0.5f * CELLS)); ix = ix < 0 ? 0 : (ix > CELLS-1 ? CELLS-1 : ix);
    int iy = (int)((py + 1.f) * (0.5f * CELLS)); iy = iy < 0 ? 0 : (iy > CELLS-1 ? CELLS-1 : iy);
    int iz = (int)((pz + 1.f) * (0.5f * CELLS)); iz = iz < 0 ? 0 : (iz > CELLS-1 ? CELLS-1 : iz);
    return (iz * CELLS + iy) * CELLS + ix;
}

__global__ __launch_bounds__(256) void count_kernel(const float* __restrict__ xs,
                                                    unsigned* __restrict__ hist) {
    unsigned pt = blockIdx.x * blockDim.x + threadIdx.x;
    atomicAdd(&hist[cell_of(xs[pt*3+0], xs[pt*3+1], xs[pt*3+2])], 1u);
}

__global__ __launch_bounds__(256) void scan_kernel(const unsigned* __restrict__ hist,
                                                   unsigned* __restrict__ cnt) {
    __shared__ unsigned part[256];
    int t = threadIdx.x;
    unsigned base = t * (NCELL / 256);
    unsigned loc[NCELL / 256];
    unsigned sum = 0;
#pragma unroll
    for (int i = 0; i < NCELL / 256; ++i) { loc[i] = sum; sum += hist[base + i]; }
    part[t] = sum;
    __syncthreads();
    for (int off = 1; off < 256; off <<= 1) {
        unsigned v = (t >= off) ? part[t - off] : 0u;
        __syncthreads();
        part[t] += v;
        __syncthreads();
    }
    unsigned prev = (t == 0) ? 0u : part[t - 1];
#pragma unroll
    for (int i = 0; i < NCELL / 256; ++i) cnt[base + i] = prev + loc[i];
}

__global__ __launch_bounds__(256) void scatter_kernel(const float* __restrict__ xs,
                                                      unsigned* __restrict__ cnt,
                                                      float4* __restrict__ sorted) {
    unsigned pt = blockIdx.x * blockDim.x + threadIdx.x;
    float px = xs[pt*3+0], py = xs[pt*3+1], pz = xs[pt*3+2];
    unsigned pos = atomicAdd(&cnt[cell_of(px, py, pz)], 1u);
    sorted[pos] = make_float4(px, py, pz, __int_as_float((int)pt));
}

// Fused: gather(paired loads) -> layer0 MFMA -> relu -> layer1 MFMA -> dot W2
__global__ __launch_bounds__(256, 4) void amgsrn_fused(
        const float4* __restrict__ sorted, const uint2* __restrict__ featP,
        const float* __restrict__ ws, const float* __restrict__ W2,
        float* __restrict__ out) {
    __shared__ uint4 SH[2048];     // 32 KB: A dbuf halves, then H0 frag-linear
    __shared__ float SOUT[256];
    const float* M = ws + OFF_M;
    const f16x8* W0f = (const f16x8*)(ws + OFF_W0F);
    const f16x8* W1f = (const f16x8*)(ws + OFF_W1F);

    int t = threadIdx.x;
    int lane = t & 63, w = t >> 6;
    int tmw = t >> 4, mrow = t & 15;

    float4 p4 = sorted[blockIdx.x * 256u + t];
    float px = p4.x, py = p4.y, pz = p4.z;
    int orig = __float_as_int(p4.w);

    f32x4 acc[4][4];
#pragma unroll
    for (int a = 0; a < 4; ++a)
#pragma unroll
        for (int b = 0; b < 4; ++b) acc[a][b] = (f32x4){0.f, 0.f, 0.f, 0.f};

    for (int kc = 0; kc < 4; ++kc) {
        uint4* buf = &SH[(kc & 1) * 1024];
#pragma unroll
        for (int c = 0; c < 4; ++c) {
            uint pk[4];
#pragma unroll
            for (int gi = 0; gi < 4; ++gi) {
                int g = kc * 16 + c * 4 + gi;
                const float* m = M + g * 12;          // uniform -> s_load
                float tx = m[0]*px + m[1]*py + m[2]*pz + m[3];
                float ty = m[4]*px + m[5]*py + m[6]*pz + m[7];
                float tz = m[8]*px + m[9]*py + m[10]*pz + m[11];
                float gx = (tx + 1.f) * (0.5f * (DIMG - 1));
                float gy = (ty + 1.f) * (0.5f * (DIMG - 1));
                float gz = (tz + 1.f) * (0.5f * (DIMG - 1));
                float f0 = 0.f, f1 = 0.f;
                if (gx > -1.f && gx < (float)DIMG && gy > -1.f && gy < (float)DIMG &&
                    gz > -1.f && gz < (float)DIMG) {
                    float x0f = floorf(gx), y0f = floorf(gy), z0f = floorf(gz);
                    float fx = gx - x0f, fy = gy - y0f, fz = gz - z0f;
                    int x0 = (int)x0f, y0 = (int)y0f, z0 = (int)z0f;
                    int x1 = x0 + 1, y1 = y0 + 1, z1 = z0 + 1;
                    float wx0 = (x0 >= 0)      ? (1.f - fx) : 0.f;
                    float wx1 = (x1 <= DIMG-1) ? fx         : 0.f;
                    float wy0 = (y0 >= 0)      ? (1.f - fy) : 0.f;
                    float wy1 = (y1 <= DIMG-1) ? fy         : 0.f;
                    float wz0 = (z0 >= 0)      ? (1.f - fz) : 0.f;
                    float wz1 = (z1 <= DIMG-1) ? fz         : 0.f;
                    int cx0 = max(x0, 0), cx1 = min(x1, DIMG-1);
                    int cy0 = max(y0, 0), cy1 = min(y1, DIMG-1);
                    int cz0 = max(z0, 0), cz1 = min(z1, DIMG-1);
                    bool adj = (cx1 == cx0 + 1);

                    const uint2* P = featP + (size_t)g * VOX;
                    int r00 = (cz0 * DIMG + cy0) * DIMG + cx0;
                    int r01 = (cz0 * DIMG + cy1) * DIMG + cx0;
                    int r10 = (cz1 * DIMG + cy0) * DIMG + cx0;
                    int r11 = (cz1 * DIMG + cy1) * DIMG + cx0;
                    uint2 e00 = P[r00], e01 = P[r01], e10 = P[r10], e11 = P[r11];
                    float2 l00 = h2f(e00.x), u00 = h2f(adj ? e00.y : e00.x);
                    float2 l01 = h2f(e01.x), u01 = h2f(adj ? e01.y : e01.x);
                    float2 l10 = h2f(e10.x), u10 = h2f(adj ? e10.y : e10.x);
                    float2 l11 = h2f(e11.x), u11 = h2f(adj ? e11.y : e11.x);

                    float w00 = wz0*wy0, w01 = wz0*wy1, w10 = wz1*wy0, w11 = wz1*wy1;
                    f0 = w00*(wx0*l00.x + wx1*u00.x) + w01*(wx0*l01.x + wx1*u01.x)
                       + w10*(wx0*l10.x + wx1*u10.x) + w11*(wx0*l11.x + wx1*u11.x);
                    f1 = w00*(wx0*l00.y + wx1*u00.y) + w01*(wx0*l01.y + wx1*u01.y)
                       + w10*(wx0*l10.y + wx1*u10.y) + w11*(wx0*l11.y + wx1*u11.y);
                }
                union { uint u; __half2 h; } pkc;
                pkc.h = __floats2half2_rn(f0, f1);
                pk[gi] = pkc.u;
            }
            buf[tmw * 64 + c * 16 + mrow] = make_uint4(pk[0], pk[1], pk[2], pk[3]);
        }
        __syncthreads();
#pragma unroll
        for (int im = 0; im < 4; ++im) {
            f16x8 af = as_f16x8(buf[(w * 4 + im) * 64 + lane]);
#pragma unroll
            for (int tn = 0; tn < 4; ++tn) {
                f16x8 bf = W0f[(tn * 4 + kc) * 64 + lane];
                acc[im][tn] = __builtin_amdgcn_mfma_f32_16x16x32_f16(af, bf, acc[im][tn], 0, 0, 0);
            }
        }
    }
    __syncthreads();

    // relu(h0) -> H0 frag-linear f16 in SH
    f16* Hh = (f16*)SH;
#pragma unroll
    for (int im = 0; im < 4; ++im) {
        int tm = w * 4 + im;
#pragma unroll
        for (int tn = 0; tn < 4; ++tn) {
            int n = tn * 16 + (lane & 15);
            int kc2 = n >> 5, koct = (n >> 3) & 3, j = n & 7;
#pragma unroll
            for (int r = 0; r < 4; ++r) {
                int mloc = (lane >> 4) * 4 + r;
                Hh[tm * 1024 + kc2 * 512 + (koct * 16 + mloc) * 8 + j] =
                    (f16)fmaxf(acc[im][tn][r], 0.f);
            }
        }
    }
    __syncthreads();

    f32x4 acc2[4][4];
#pragma unroll
    for (int a = 0; a < 4; ++a)
#pragma unroll
        for (int b = 0; b < 4; ++b) acc2[a][b] = (f32x4){0.f, 0.f, 0.f, 0.f};
#pragma unroll
    for (int kc2 = 0; kc2 < 2; ++kc2) {
#pragma unroll
        for (int im = 0; im < 4; ++im) {
            f16x8 af = as_f16x8(SH[(w * 4 + im) * 128 + kc2 * 64 + lane]);
#pragma unroll
            for (int tn = 0; tn < 4; ++tn) {
                f16x8 bf = W1f[(tn * 2 + kc2) * 64 + lane];
                acc2[im][tn] = __builtin_amdgcn_mfma_f32_16x16x32_f16(af, bf, acc2[im][tn], 0, 0, 0);
            }
        }
    }

    float w2v[4];
#pragma unroll
    for (int tn = 0; tn < 4; ++tn) w2v[tn] = W2[tn * 16 + (lane & 15)];
    __syncthreads();
#pragma unroll
    for (int im = 0; im < 4; ++im) {
#pragma unroll
        for (int r = 0; r < 4; ++r) {
            float pp = 0.f;
#pragma unroll
            for (int tn = 0; tn < 4; ++tn) pp += fmaxf(acc2[im][tn][r], 0.f) * w2v[tn];
            pp += __shfl_xor(pp, 1);
            pp += __shfl_xor(pp, 2);
            pp += __shfl_xor(pp, 4);
            pp += __shfl_xor(pp, 8);
            if ((lane & 15) == 0)
                SOUT[w * 64 + im * 16 + (lane >> 4) * 4 + r] = pp;
        }
    }
    __syncthreads();
    out[orig] = SOUT[t];
}

// ---------------- fallback (fp32, unsorted; needs only M in ws) ----------------
__global__ __launch_bounds__(256) void amgsrn_fallback(
        const float* __restrict__ xs, const float* __restrict__ feat,
        const float* __restrict__ ws, const float* __restrict__ W0,
        const float* __restrict__ W1, const float* __restrict__ W2,
        float* __restrict__ out) {
    const float* M = ws + OFF_M;
    unsigned pt = blockIdx.x * blockDim.x + threadIdx.x;
    float px = xs[pt*3+0], py = xs[pt*3+1], pz = xs[pt*3+2];
    float h0[NN];
#pragma unroll
    for (int j = 0; j < NN; ++j) h0[j] = 0.f;
    for (int g = 0; g < NG; ++g) {
        const float* m = M + g * 12;
        float tx = m[0]*px + m[1]*py + m[2]*pz + m[3];
        float ty = m[4]*px + m[5]*py + m[6]*pz + m[7];
        float tz = m[8]*px + m[9]*py + m[10]*pz + m[11];
        float gx = (tx + 1.f) * (0.5f * (DIMG - 1));
        float gy = (ty + 1.f) * (0.5f * (DIMG - 1));
        float gz = (tz + 1.f) * (0.5f * (DIMG - 1));
        float f0 = 0.f, f1 = 0.f;
        if (gx > -1.f && gx < (float)DIMG && gy > -1.f && gy < (float)DIMG &&
            gz > -1.f && gz < (float)DIMG) {
            float x0f = floorf(gx), y0f = floorf(gy), z0f = floorf(gz);
            float fx = gx - x0f, fy = gy - y0f, fz = gz - z0f;
            int x0 = (int)x0f, y0 = (int)y0f, z0 = (int)z0f;
            int x1 = x0 + 1, y1 = y0 + 1, z1 = z0 + 1;
            float wx0 = (x0 >= 0)      ? (1.f - fx) : 0.f;
            float wx1 = (x1 <= DIMG-1) ? fx         : 0.f;
            float wy0 = (y0 >= 0)      ? (1.f - fy) : 0.f;
            float wy1 = (y1 <= DIMG-1) ? fy         : 0.f;
            float wz0 = (z0 >= 0)      ? (1.f - fz) : 0.f;
            float wz1 = (z1 <= DIMG-1) ? fz         : 0.f;
            int cx0 = max(x0, 0), cx1 = min(x1, DIMG-1);
            int cy0 = max(y0, 0), cy1 = min(y1, DIMG-1);
            int cz0 = max(z0, 0), cz1 = min(z1, DIMG-1);
            const float* b0 = feat + (size_t)g * (NC * VOX);
            const float* b1 = b0 + VOX;
            int r00 = (cz0 * DIMG + cy0) * DIMG;
            int r01 = (cz0 * DIMG + cy1) * DIMG;
            int r10 = (cz1 * DIMG + cy0) * DIMG;
            int r11 = (cz1 * DIMG + cy1) * DIMG;
            f0 = wz0*(wy0*(wx0*b0[r00+cx0] + wx1*b0[r00+cx1]) + wy1*(wx0*b0[r01+cx0] + wx1*b0[r01+cx1]))
               + wz1*(wy0*(wx0*b0[r10+cx0] + wx1*b0[r10+cx1]) + wy1*(wx0*b0[r11+cx0] + wx1*b0[r11+cx1]));
            f1 = wz0*(wy0*(wx0*b1[r00+cx0] + wx1*b1[r00+cx1]) + wy1*(wx0*b1[r01+cx0] + wx1*b1[r01+cx1]))
               + wz1*(wy0*(wx0*b1[r10+cx0] + wx1*b1[r10+cx1]) + wy1*(wx0*b1[r11+cx0] + wx1*b1[r11+cx1]));
        }
#pragma unroll
        for (int j = 0; j < NN; ++j) {
            h0[j] = fmaf(f0, W0[j*DIN + g*2 + 0], h0[j]);
            h0[j] = fmaf(f1, W0[j*DIN + g*2 + 1], h0[j]);
        }
    }
#pragma unroll
    for (int j = 0; j < NN; ++j) h0[j] = fmaxf(h0[j], 0.f);
    float outv = 0.f;
    for (int j = 0; j < NN; ++j) {
        float acc = 0.f;
#pragma unroll
        for (int k = 0; k < NN; ++k) acc = fmaf(h0[k], W1[j*NN + k], acc);
        outv = fmaf(fmaxf(acc, 0.f), W2[j], outv);
    }
    out[pt] = outv;
}

extern "C" void kernel_launch(void* const* d_in, const int* in_sizes, int n_in,
                              void* d_out, int out_size, void* d_ws, size_t ws_size,
                              hipStream_t stream) {
    const float* x    = (const float*)d_in[0];
    const float* r    = (const float*)d_in[1];
    const float* s    = (const float*)d_in[2];
    const float* t    = (const float*)d_in[3];
    const float* feat = (const float*)d_in[4];
    const float* W0   = (const float*)d_in[5];
    const float* W1   = (const float*)d_in[6];
    const float* W2   = (const float*)d_in[7];
    float* outp = (float*)d_out;
    float* ws   = (float*)d_ws;

    prep_kernel<<<64, 256, 0, stream>>>(r, s, t, W0, W1, ws);

    if (ws_size >= WS_REQ_BYTES) {
        unsigned* hist   = (unsigned*)(ws + OFF_HIST);
        unsigned* cnt    = (unsigned*)(ws + OFF_CNT);
        float4*   sorted = (float4*)(ws + OFF_SORT);
        uint4*    featP4 = (uint4*)(ws + OFF_FEATP);

        hipMemsetAsync(hist, 0, NCELL * sizeof(unsigned), stream);
        repack_pairs<<<(NG * VOX / 4) / 256, 256, 0, stream>>>(feat, featP4);
        count_kernel<<<NPTS / 256, 256, 0, stream>>>(x, hist);
        scan_kernel<<<1, 256, 0, stream>>>(hist, cnt);
        scatter_kernel<<<NPTS / 256, 256, 0, stream>>>(x, cnt, sorted);
        amgsrn_fused<<<NPTS / 256, 256, 0, stream>>>(sorted, (const uint2*)featP4, ws, W2, outp);
    } else {
        amgsrn_fallback<<<NPTS / 256, 256, 0, stream>>>(x, feat, ws, W0, W1, W2, outp);
    }
}